// Round 1
// baseline (13.222 us; speedup 1.0000x reference)
//
#include <hip/hip_runtime.h>

// QuanvolutionClassifier, closed form.
//
// Derivation: RY(x)|0> = [cos(x/2), sin(x/2)]. RZ phases are unit-modulus and
// CNOT(0,1)/CNOT(2,3) merely permute computational-basis indices
// (j -> j^i, l -> l^k), so |amplitude|^2 after the circuit is
//   P[i,j,k,l] = q0[i]^2 * q1[j^i]^2 * q2[k]^2 * q3[l^k]^2   (theta drops out).
// Hence  <Z0>=cos(a), <Z1>=cos(a)cos(b), <Z2>=cos(c), <Z3>=cos(c)cos(d)
// for the 2x2 patch [a b; c d]. Then logits = feats @ W^T + bias, log_softmax.

__global__ __launch_bounds__(256) void quanv_fused(
    const float* __restrict__ x,     // [B, 784]
    const float* __restrict__ W,     // [10, 784]
    const float* __restrict__ bias,  // [10]
    float* __restrict__ out,         // [B, 10]
    int B)
{
    const int tid  = threadIdx.x;
    const int wv   = tid >> 6;        // wave within block: 0..3
    const int lane = tid & 63;
    const int row  = (blockIdx.x << 2) + wv;   // one wave per batch row
    if (row >= B) return;

    const float2* __restrict__ xr2 =
        reinterpret_cast<const float2*>(x + (size_t)row * 784);

    float acc[10];
#pragma unroll
    for (int c = 0; c < 10; ++c) acc[c] = 0.0f;

    // 196 patches, strided by wave width
#pragma unroll
    for (int it = 0; it < 4; ++it) {
        const int p = lane + (it << 6);
        if (p < 196) {
            const int pr = p / 14;
            const int pc = p - pr * 14;
            const int t2 = pr * 28 + pc;           // float2 index of top pair
            const float2 top = xr2[t2];            // img[2r][2c], img[2r][2c+1]
            const float2 bot = xr2[t2 + 14];       // img[2r+1][2c], img[2r+1][2c+1]
            const float f0 = __cosf(top.x);
            const float f1 = f0 * __cosf(top.y);
            const float f2 = __cosf(bot.x);
            const float f3 = f2 * __cosf(bot.y);
#pragma unroll
            for (int c = 0; c < 10; ++c) {
                const float4 w =
                    reinterpret_cast<const float4*>(W + c * 784)[p];  // 16B-aligned
                acc[c] = fmaf(f0, w.x,
                         fmaf(f1, w.y,
                         fmaf(f2, w.z,
                         fmaf(f3, w.w, acc[c]))));
            }
        }
    }

    // butterfly reduce the 10 class partials across the wave (64 lanes)
#pragma unroll
    for (int off = 32; off > 0; off >>= 1) {
#pragma unroll
        for (int c = 0; c < 10; ++c)
            acc[c] += __shfl_xor(acc[c], off, 64);
    }

    if (lane == 0) {
        float m = -3.4e38f;
#pragma unroll
        for (int c = 0; c < 10; ++c) {
            acc[c] += bias[c];
            m = fmaxf(m, acc[c]);
        }
        float s = 0.0f;
#pragma unroll
        for (int c = 0; c < 10; ++c) s += __expf(acc[c] - m);
        const float lse = m + __logf(s);
        float* __restrict__ o = out + (size_t)row * 10;
#pragma unroll
        for (int c = 0; c < 10; ++c) o[c] = acc[c] - lse;
    }
}

extern "C" void kernel_launch(void* const* d_in, const int* in_sizes, int n_in,
                              void* d_out, int out_size, void* d_ws, size_t ws_size,
                              hipStream_t stream) {
    const float* x   = (const float*)d_in[0];
    // d_in[1] = theta: provably unused (RZ phases cancel in |amp|^2 after CNOT
    // basis permutation — see derivation above).
    const float* W   = (const float*)d_in[2];
    const float* b   = (const float*)d_in[3];
    float* out       = (float*)d_out;

    const int B = in_sizes[0] / 784;
    const int blocks = (B + 3) / 4;   // 4 rows (waves) per block
    quanv_fused<<<blocks, 256, 0, stream>>>(x, W, b, out, B);
}

// Round 3
// 12.442 us; speedup vs baseline: 1.0627x; 1.0627x over previous
//
#include <hip/hip_runtime.h>

// QuanvolutionClassifier, closed form.
//
// Derivation: RY(x)|0> = [cos(x/2), sin(x/2)]. RZ phases are unit-modulus and
// CNOT(0,1)/CNOT(2,3) merely permute computational-basis indices
// (j -> j^i, l -> l^k), so |amplitude|^2 after the circuit is
//   P[i,j,k,l] = q0[i]^2 * q1[j^i]^2 * q2[k]^2 * q3[l^k]^2   (theta drops out).
// Hence  <Z0>=cos(a), <Z1>=cos(a)cos(b), <Z2>=cos(c), <Z3>=cos(c)cos(d)
// for the 2x2 patch [a b; c d]. Then logits = feats @ W^T + bias, log_softmax.
//
// R2/R3: W staged in LDS (31.4 KB) — per-row W re-reads were ~40 KB/row from
// L1/L2 (128 MB total) and W thrashed out of the 32 KB L1 under the x stream.
// ds_read_b128 with one base VGPR (lane*16) + immediate offsets replaces all
// W address arithmetic. x loads are nontemporal (streamed once) so they don't
// evict anything. R3 fix: nontemporal builtin needs a native clang vector
// type, not HIP's float2 class — use ext_vector_type(2).

typedef float f32x2 __attribute__((ext_vector_type(2)));

__global__ __launch_bounds__(256, 4) void quanv_fused(
    const float* __restrict__ x,     // [B, 784]
    const float* __restrict__ W,     // [10, 784]
    const float* __restrict__ bias,  // [10]
    float* __restrict__ out,         // [B, 10]
    int B)
{
    __shared__ float Wl[7840];       // [10][784]
    __shared__ float bl[10];

    const int tid = threadIdx.x;

    // stage W into LDS, coalesced float4 (1960 float4 over 256 threads)
    {
        const float4* __restrict__ Wg4 = reinterpret_cast<const float4*>(W);
        float4* Wl4 = reinterpret_cast<float4*>(Wl);
        for (int i = tid; i < 1960; i += 256) Wl4[i] = Wg4[i];
        if (tid < 10) bl[tid] = bias[tid];
    }
    __syncthreads();

    const int wv   = tid >> 6;        // wave within block: 0..3
    const int lane = tid & 63;
    const int row  = (blockIdx.x << 2) + wv;   // one wave per batch row

    if (row < B) {
        const f32x2* __restrict__ xr2 =
            reinterpret_cast<const f32x2*>(x + (size_t)row * 784);
        const float* __restrict__ wl = Wl + (lane << 2);  // base: &Wl[lane*4]

        float acc[10];
#pragma unroll
        for (int c = 0; c < 10; ++c) acc[c] = 0.0f;

        // 196 patches, strided by wave width
#pragma unroll
        for (int it = 0; it < 4; ++it) {
            const int p = lane + (it << 6);
            if (p < 196) {                       // branch-free for it<3
                const int pr = p / 14;
                const int pc = p - pr * 14;
                const int t2 = pr * 28 + pc;     // float2 index of top pair
                const f32x2 top = __builtin_nontemporal_load(&xr2[t2]);
                const f32x2 bot = __builtin_nontemporal_load(&xr2[t2 + 14]);
                const float f0 = __cosf(top.x);
                const float f1 = f0 * __cosf(top.y);
                const float f2 = __cosf(bot.x);
                const float f3 = f2 * __cosf(bot.y);
#pragma unroll
                for (int c = 0; c < 10; ++c) {
                    // ds_read_b128, immediate offset = it*1024 + c*3136 bytes
                    const float4 w = *reinterpret_cast<const float4*>(
                        wl + (it << 8) + c * 784);
                    acc[c] = fmaf(f0, w.x,
                             fmaf(f1, w.y,
                             fmaf(f2, w.z,
                             fmaf(f3, w.w, acc[c]))));
                }
            }
        }

        // butterfly reduce the 10 class partials across the wave (64 lanes)
#pragma unroll
        for (int off = 32; off > 0; off >>= 1) {
#pragma unroll
            for (int c = 0; c < 10; ++c)
                acc[c] += __shfl_xor(acc[c], off, 64);
        }

        if (lane == 0) {
            float m = -3.4e38f;
#pragma unroll
            for (int c = 0; c < 10; ++c) {
                acc[c] += bl[c];
                m = fmaxf(m, acc[c]);
            }
            float s = 0.0f;
#pragma unroll
            for (int c = 0; c < 10; ++c) s += __expf(acc[c] - m);
            const float lse = m + __logf(s);
            float* __restrict__ o = out + (size_t)row * 10;
#pragma unroll
            for (int c = 0; c < 10; ++c) o[c] = acc[c] - lse;
        }
    }
}

extern "C" void kernel_launch(void* const* d_in, const int* in_sizes, int n_in,
                              void* d_out, int out_size, void* d_ws, size_t ws_size,
                              hipStream_t stream) {
    const float* x   = (const float*)d_in[0];
    // d_in[1] = theta: provably unused (RZ phases cancel in |amp|^2 after CNOT
    // basis permutation — see derivation above).
    const float* W   = (const float*)d_in[2];
    const float* b   = (const float*)d_in[3];
    float* out       = (float*)d_out;

    const int B = in_sizes[0] / 784;
    const int blocks = (B + 3) / 4;   // 4 rows (waves) per block
    quanv_fused<<<blocks, 256, 0, stream>>>(x, W, b, out, B);
}